// Round 13
// baseline (2323.782 us; speedup 1.0000x reference)
//
#include <hip/hip_runtime.h>

#define DD 128
#define BCAP 64
#define OCAP 4096
#define BUCKET_REP 60   // measurement: isolate returning-atomicAdd cost
#define APPLY_REP  20   // measurement: pin apply_mfma cost

typedef float vfloat4 __attribute__((ext_vector_type(4)));
typedef __attribute__((ext_vector_type(8))) short short8;   // 8 bf16 = 4 VGPRs
typedef __attribute__((ext_vector_type(4))) float f32x4;    // MFMA accumulator

__device__ inline float4 ntload4(const float* p) {
    vfloat4 v = __builtin_nontemporal_load(reinterpret_cast<const vfloat4*>(p));
    return make_float4(v.x, v.y, v.z, v.w);
}

// round-to-nearest-even f32 -> bf16 (as ushort)
__device__ inline ushort f2bf(float f) {
    unsigned x = __float_as_uint(f);
    return (ushort)((x + 0x7FFFu + ((x >> 16) & 1u)) >> 16);
}

// ---------------------------------------------------------------------------
// K1: per-node dots s[n]=h·aw_src, t[n]=h·aw_dst+attn_b; zeroes count[n];
// writes h16. Tail blocks cast W -> W16. gid 0 zeroes the overflow counter.
// ---------------------------------------------------------------------------
__global__ __launch_bounds__(256) void k_node_dots(
    const float* __restrict__ h, const float* __restrict__ attn_w,
    const float* __restrict__ attn_b,
    float* __restrict__ s, float* __restrict__ t,
    int* __restrict__ count, ushort* __restrict__ h16,
    int n_nodes, int n_node_blocks,
    const float* __restrict__ W, ushort* __restrict__ W16,
    int* __restrict__ ovf_cnt)
{
    if (blockIdx.x >= n_node_blocks) {
        int idx = (blockIdx.x - n_node_blocks) * 256 + threadIdx.x;
        if (idx < 128 * 256) W16[idx] = f2bf(W[idx]);
        return;
    }
    int gid  = blockIdx.x * blockDim.x + threadIdx.x;
    if (gid == 0) *ovf_cnt = 0;
    int node = gid >> 6;
    int lane = threadIdx.x & 63;
    if (node >= n_nodes) return;
    const float2 hv = *reinterpret_cast<const float2*>(h + (size_t)node * DD + lane * 2);
    const float2 as = *reinterpret_cast<const float2*>(attn_w + lane * 2);
    const float2 ad = *reinterpret_cast<const float2*>(attn_w + DD + lane * 2);
    ushort2 hb; hb.x = f2bf(hv.x); hb.y = f2bf(hv.y);
    *reinterpret_cast<ushort2*>(h16 + (size_t)node * DD + lane * 2) = hb;
    float sa = hv.x * as.x + hv.y * as.y;
    float ta = hv.x * ad.x + hv.y * ad.y;
    #pragma unroll
    for (int off = 32; off > 0; off >>= 1) {
        sa += __shfl_down(sa, off);
        ta += __shfl_down(ta, off);
    }
    if (lane == 0) { s[node] = sa; t[node] = ta + attn_b[0]; count[node] = 0; }
}

// ---------------------------------------------------------------------------
// K2: bucketize — replaces hist+scan+scatter. rank = returning atomicAdd;
// edge lands at os[dst*64 + rank]; rank >= 64 spills to overflow list.
// The rep loop isolates the returning-atomic cost (scratch = throwaway).
// ---------------------------------------------------------------------------
__global__ __launch_bounds__(256) void k_bucket(
    const int* __restrict__ dst, const int* __restrict__ src,
    const float* __restrict__ s, const float* __restrict__ t,
    int* __restrict__ count, int* __restrict__ scratch,
    int2* __restrict__ os, int* __restrict__ ovf_cnt, int4* __restrict__ ovf,
    int n_edges)
{
    int e = blockIdx.x * blockDim.x + threadIdx.x;
    if (e >= n_edges) return;
    int d = dst[e];
    float sc = fmaxf(s[src[e]] + t[d], 0.f);
    #pragma unroll 1
    for (int rep = 0; rep < BUCKET_REP - 1; ++rep) {   // measurement only
        int r = atomicAdd(scratch + d, 1);
        asm volatile("" :: "v"(r));
    }
    int r = atomicAdd(count + d, 1);
    if (r < BCAP) {
        int2 v; v.x = e; v.y = __float_as_int(sc);
        os[(size_t)d * BCAP + r] = v;
    } else {
        int oi = atomicAdd(ovf_cnt, 1);
        if (oi < OCAP) {
            int4 v; v.x = d; v.y = e; v.z = __float_as_int(sc); v.w = 0;
            ovf[oi] = v;
        }
    }
}

// ---------------------------------------------------------------------------
// K3: fused per-node attention from buckets. deg = count[node]; fast path
// deg <= 64 (always, in practice); slow path adds overflow-list edges.
// ---------------------------------------------------------------------------
__global__ __launch_bounds__(256) void k_fused(
    const int* __restrict__ count, const int2* __restrict__ os,
    const float* __restrict__ ef,
    const int* __restrict__ ovf_cnt, const int4* __restrict__ ovf,
    ushort* __restrict__ u16, int n_nodes)
{
    int node = blockIdx.x * (blockDim.x >> 6) + (threadIdx.x >> 6);
    int lane = threadIdx.x & 63;
    if (node >= n_nodes) return;
    int deg = count[node];
    const int2* bos = os + (size_t)node * BCAP;

    if (deg <= 64) {
        int2 os_l = make_int2(0, 0);
        if (lane < deg) os_l = bos[lane];
        int   e_l = os_l.x;
        float pe  = (lane < deg) ? expf(__int_as_float(os_l.y)) : 0.f;
        float sum = pe;
        #pragma unroll
        for (int off = 32; off > 0; off >>= 1) sum += __shfl_xor(sum, off);
        float inv  = sum > 0.f ? 1.f / sum : 0.f;
        float pw_l = pe * inv;

        int grp = lane >> 3, sub = lane & 7;
        float4 a0 = make_float4(0.f, 0.f, 0.f, 0.f);
        float4 a1 = a0, a2 = a0, a3 = a0;
        int kmax = (deg + 7) >> 3;
        for (int k = 0; k < kmax; ++k) {
            int j  = grp + 8 * k;
            int jj = (j < deg) ? j : 0;
            int   e  = __shfl(e_l, jj);
            float pw = __shfl(pw_l, jj);
            if (j < deg) {
                const float* er = ef + (size_t)e * DD;
                float4 v0 = ntload4(er + sub * 4);
                float4 v1 = ntload4(er + 32 + sub * 4);
                float4 v2 = ntload4(er + 64 + sub * 4);
                float4 v3 = ntload4(er + 96 + sub * 4);
                a0.x = fmaf(pw, v0.x, a0.x); a0.y = fmaf(pw, v0.y, a0.y);
                a0.z = fmaf(pw, v0.z, a0.z); a0.w = fmaf(pw, v0.w, a0.w);
                a1.x = fmaf(pw, v1.x, a1.x); a1.y = fmaf(pw, v1.y, a1.y);
                a1.z = fmaf(pw, v1.z, a1.z); a1.w = fmaf(pw, v1.w, a1.w);
                a2.x = fmaf(pw, v2.x, a2.x); a2.y = fmaf(pw, v2.y, a2.y);
                a2.z = fmaf(pw, v2.z, a2.z); a2.w = fmaf(pw, v2.w, a2.w);
                a3.x = fmaf(pw, v3.x, a3.x); a3.y = fmaf(pw, v3.y, a3.y);
                a3.z = fmaf(pw, v3.z, a3.z); a3.w = fmaf(pw, v3.w, a3.w);
            }
        }
        #pragma unroll
        for (int off = 8; off <= 32; off <<= 1) {
            a0.x += __shfl_xor(a0.x, off); a0.y += __shfl_xor(a0.y, off);
            a0.z += __shfl_xor(a0.z, off); a0.w += __shfl_xor(a0.w, off);
            a1.x += __shfl_xor(a1.x, off); a1.y += __shfl_xor(a1.y, off);
            a1.z += __shfl_xor(a1.z, off); a1.w += __shfl_xor(a1.w, off);
            a2.x += __shfl_xor(a2.x, off); a2.y += __shfl_xor(a2.y, off);
            a2.z += __shfl_xor(a2.z, off); a2.w += __shfl_xor(a2.w, off);
            a3.x += __shfl_xor(a3.x, off); a3.y += __shfl_xor(a3.y, off);
            a3.z += __shfl_xor(a3.z, off); a3.w += __shfl_xor(a3.w, off);
        }
        if (lane < 8) {
            ushort* ur = u16 + (size_t)node * DD;
            *reinterpret_cast<ushort4*>(ur + 4 * sub) =
                make_ushort4(f2bf(a0.x), f2bf(a0.y), f2bf(a0.z), f2bf(a0.w));
            *reinterpret_cast<ushort4*>(ur + 32 + 4 * sub) =
                make_ushort4(f2bf(a1.x), f2bf(a1.y), f2bf(a1.z), f2bf(a1.w));
            *reinterpret_cast<ushort4*>(ur + 64 + 4 * sub) =
                make_ushort4(f2bf(a2.x), f2bf(a2.y), f2bf(a2.z), f2bf(a2.w));
            *reinterpret_cast<ushort4*>(ur + 96 + 4 * sub) =
                make_ushort4(f2bf(a3.x), f2bf(a3.y), f2bf(a3.z), f2bf(a3.w));
        }
    } else {
        // ---- overflow path (deg > 64): bucket holds 64, rest in ovf list ----
        int novf = min(*ovf_cnt, OCAP);
        int2 os_l = bos[lane];                       // all 64 slots valid
        float pe  = expf(__int_as_float(os_l.y));
        float sum = pe;
        for (int i = lane; i < novf; i += 64) {
            int4 v = ovf[i];
            if (v.x == node) sum += expf(__int_as_float(v.z));
        }
        #pragma unroll
        for (int off = 32; off > 0; off >>= 1) sum += __shfl_xor(sum, off);
        float inv = sum > 0.f ? 1.f / sum : 0.f;

        float2 acc = make_float2(0.f, 0.f);
        int   e_l = os_l.x;
        float p_l = pe * inv;
        for (int j = 0; j < 64; ++j) {
            int   e  = __shfl(e_l, j);
            float pw = __shfl(p_l, j);
            float2 vv = *reinterpret_cast<const float2*>(ef + (size_t)e * DD + lane * 2);
            acc.x = fmaf(pw, vv.x, acc.x);
            acc.y = fmaf(pw, vv.y, acc.y);
        }
        for (int j = 0; j < novf; ++j) {             // scalar; novf ~ 0
            int4 v = ovf[j];
            if (v.x == node) {
                float pw = expf(__int_as_float(v.z)) * inv;
                float2 vv = *reinterpret_cast<const float2*>(ef + (size_t)v.y * DD + lane * 2);
                acc.x = fmaf(pw, vv.x, acc.x);
                acc.y = fmaf(pw, vv.y, acc.y);
            }
        }
        ushort2 uu; uu.x = f2bf(acc.x); uu.y = f2bf(acc.y);
        *reinterpret_cast<ushort2*>(u16 + (size_t)node * DD + lane * 2) = uu;
    }
}

// ---------------------------------------------------------------------------
// K4: out = relu([h16|u16] @ W16^T + b) via bf16 MFMA. Rep'd for measurement.
// ---------------------------------------------------------------------------
__global__ __launch_bounds__(256) void k_apply_mfma(
    const ushort* __restrict__ h16, const ushort* __restrict__ u16,
    const ushort* __restrict__ W16, const float* __restrict__ b,
    float* __restrict__ out, int n_nodes)
{
    int wave = threadIdx.x >> 6;
    int lane = threadIdx.x & 63;
    int nodeBase = blockIdx.x * 64 + wave * 16;
    int row  = lane & 15;
    int quad = lane >> 4;
    int node = nodeBase + row;
    if (node >= n_nodes) node = n_nodes - 1;   // clamp loads; stores guarded

    for (int rep = 0; rep < APPLY_REP; ++rep) {
        f32x4 acc[8];
        #pragma unroll
        for (int ct = 0; ct < 8; ++ct) acc[ct] = (f32x4){0.f, 0.f, 0.f, 0.f};

        #pragma unroll
        for (int kc = 0; kc < 8; ++kc) {
            const ushort* abase = (kc < 4)
                ? (h16 + (size_t)node * DD + kc * 32 + quad * 8)
                : (u16 + (size_t)node * DD + (kc - 4) * 32 + quad * 8);
            short8 a = *reinterpret_cast<const short8*>(abase);
            #pragma unroll
            for (int ct = 0; ct < 8; ++ct) {
                const ushort* wb = W16 + ((size_t)(ct * 16 + row)) * 256 + kc * 32 + quad * 8;
                short8 bb = *reinterpret_cast<const short8*>(wb);
                acc[ct] = __builtin_amdgcn_mfma_f32_16x16x32_bf16(a, bb, acc[ct], 0, 0, 0);
            }
        }

        #pragma unroll
        for (int ct = 0; ct < 8; ++ct) {
            int col = ct * 16 + row;
            float bk = b[col];
            #pragma unroll
            for (int r = 0; r < 4; ++r) {
                int n = nodeBase + quad * 4 + r;
                if (n < n_nodes)
                    out[(size_t)n * DD + col] = fmaxf(acc[ct][r] + bk, 0.f);
            }
        }
        asm volatile("" ::: "memory");
    }
}

// ---------------------------------------------------------------------------
extern "C" void kernel_launch(void* const* d_in, const int* in_sizes, int n_in,
                              void* d_out, int out_size, void* d_ws, size_t ws_size,
                              hipStream_t stream)
{
    const float* nfeats = (const float*)d_in[0];
    const float* efeats = (const float*)d_in[1];
    const float* W      = (const float*)d_in[2];
    const float* Wb     = (const float*)d_in[3];
    const float* attn_w = (const float*)d_in[4];
    const float* attn_b = (const float*)d_in[5];
    const int*   src    = (const int*)d_in[6];
    const int*   dst    = (const int*)d_in[7];

    const int n_nodes = in_sizes[0] / DD;
    const int n_edges = in_sizes[6];
    const int NDB = (n_nodes + 3) / 4;

    // workspace layout (os_buf 8B-aligned, ovf 16B-aligned)
    char* wsb = (char*)d_ws;
    float*  s_buf   = (float*)wsb;                       wsb += (size_t)n_nodes * 4;
    float*  t_buf   = (float*)wsb;                       wsb += (size_t)n_nodes * 4;
    int*    count   = (int*)wsb;                         wsb += (size_t)n_nodes * 4;
    int*    scratch = (int*)wsb;                         wsb += (size_t)n_nodes * 4;
    int2*   os_buf  = (int2*)wsb;                        wsb += (size_t)n_nodes * BCAP * 8;
    ushort* h16     = (ushort*)wsb;                      wsb += (size_t)n_nodes * DD * 2;
    ushort* u16     = (ushort*)wsb;                      wsb += (size_t)n_nodes * DD * 2;
    ushort* W16     = (ushort*)wsb;                      wsb += (size_t)128 * 256 * 2;
    int4*   ovf     = (int4*)wsb;                        wsb += (size_t)OCAP * 16;
    int*    ovf_cnt = (int*)wsb;                         wsb += 16;

    k_node_dots<<<NDB + 128, 256, 0, stream>>>(nfeats, attn_w, attn_b, s_buf, t_buf,
                                               count, h16, n_nodes, NDB, W, W16, ovf_cnt);
    k_bucket<<<(n_edges + 255) / 256, 256, 0, stream>>>(dst, src, s_buf, t_buf,
                                                        count, scratch, os_buf,
                                                        ovf_cnt, ovf, n_edges);
    k_fused<<<(n_nodes + 3) / 4, 256, 0, stream>>>(count, os_buf, efeats,
                                                   ovf_cnt, ovf, u16, n_nodes);
    k_apply_mfma<<<(n_nodes + 63) / 64, 256, 0, stream>>>(h16, u16, W16, Wb,
                                                          (float*)d_out, n_nodes);
}

// Round 14
// 172.237 us; speedup vs baseline: 13.4918x; 13.4918x over previous
//
#include <hip/hip_runtime.h>

#define DD 128
#define BCAP 64
#define OCAP 4096

typedef float vfloat4 __attribute__((ext_vector_type(4)));
typedef __attribute__((ext_vector_type(8))) short short8;   // 8 bf16 = 4 VGPRs
typedef __attribute__((ext_vector_type(4))) float f32x4;    // MFMA accumulator

__device__ inline float4 ntload4(const float* p) {
    vfloat4 v = __builtin_nontemporal_load(reinterpret_cast<const vfloat4*>(p));
    return make_float4(v.x, v.y, v.z, v.w);
}

// round-to-nearest-even f32 -> bf16 (as ushort)
__device__ inline ushort f2bf(float f) {
    unsigned x = __float_as_uint(f);
    return (ushort)((x + 0x7FFFu + ((x >> 16) & 1u)) >> 16);
}

// ---------------------------------------------------------------------------
// K1: per-node dots s[n]=h·aw_src, t[n]=h·aw_dst+attn_b; zeroes count[n];
// writes h16. Tail blocks cast W -> W16. gid 0 zeroes the overflow counter.
// ---------------------------------------------------------------------------
__global__ __launch_bounds__(256) void k_node_dots(
    const float* __restrict__ h, const float* __restrict__ attn_w,
    const float* __restrict__ attn_b,
    float* __restrict__ s, float* __restrict__ t,
    int* __restrict__ count, ushort* __restrict__ h16,
    int n_nodes, int n_node_blocks,
    const float* __restrict__ W, ushort* __restrict__ W16,
    int* __restrict__ ovf_cnt)
{
    if (blockIdx.x >= n_node_blocks) {
        int idx = (blockIdx.x - n_node_blocks) * 256 + threadIdx.x;
        if (idx < 128 * 256) W16[idx] = f2bf(W[idx]);
        return;
    }
    int gid  = blockIdx.x * blockDim.x + threadIdx.x;
    if (gid == 0) *ovf_cnt = 0;
    int node = gid >> 6;
    int lane = threadIdx.x & 63;
    if (node >= n_nodes) return;
    const float2 hv = *reinterpret_cast<const float2*>(h + (size_t)node * DD + lane * 2);
    const float2 as = *reinterpret_cast<const float2*>(attn_w + lane * 2);
    const float2 ad = *reinterpret_cast<const float2*>(attn_w + DD + lane * 2);
    ushort2 hb; hb.x = f2bf(hv.x); hb.y = f2bf(hv.y);
    *reinterpret_cast<ushort2*>(h16 + (size_t)node * DD + lane * 2) = hb;
    float sa = hv.x * as.x + hv.y * as.y;
    float ta = hv.x * ad.x + hv.y * ad.y;
    #pragma unroll
    for (int off = 32; off > 0; off >>= 1) {
        sa += __shfl_down(sa, off);
        ta += __shfl_down(ta, off);
    }
    if (lane == 0) { s[node] = sa; t[node] = ta + attn_b[0]; count[node] = 0; }
}

// ---------------------------------------------------------------------------
// K2: bucketize (replaces hist+scan+scatter): rank = returning atomicAdd,
// edge {id,score} lands at os[dst*64+rank]; rank >= 64 spills to overflow.
// ~35 us measured: bound by atomic write-through, structural minimum here.
// ---------------------------------------------------------------------------
__global__ __launch_bounds__(256) void k_bucket(
    const int* __restrict__ dst, const int* __restrict__ src,
    const float* __restrict__ s, const float* __restrict__ t,
    int* __restrict__ count,
    int2* __restrict__ os, int* __restrict__ ovf_cnt, int4* __restrict__ ovf,
    int n_edges)
{
    int e = blockIdx.x * blockDim.x + threadIdx.x;
    if (e >= n_edges) return;
    int d = dst[e];
    float sc = fmaxf(s[src[e]] + t[d], 0.f);
    int r = atomicAdd(count + d, 1);
    if (r < BCAP) {
        int2 v; v.x = e; v.y = __float_as_int(sc);
        os[(size_t)d * BCAP + r] = v;
    } else {
        int oi = atomicAdd(ovf_cnt, 1);
        if (oi < OCAP) {
            int4 v; v.x = d; v.y = e; v.z = __float_as_int(sc); v.w = 0;
            ovf[oi] = v;
        }
    }
}

// ---------------------------------------------------------------------------
// K3: fused per-node attention from buckets (measured ~64 us = HBM roofline
// on the mandatory 410 MB efeats read). deg<=64 fast path is register-only.
// ---------------------------------------------------------------------------
__global__ __launch_bounds__(256) void k_fused(
    const int* __restrict__ count, const int2* __restrict__ os,
    const float* __restrict__ ef,
    const int* __restrict__ ovf_cnt, const int4* __restrict__ ovf,
    ushort* __restrict__ u16, int n_nodes)
{
    int node = blockIdx.x * (blockDim.x >> 6) + (threadIdx.x >> 6);
    int lane = threadIdx.x & 63;
    if (node >= n_nodes) return;
    int deg = count[node];
    const int2* bos = os + (size_t)node * BCAP;

    if (deg <= 64) {
        int2 os_l = make_int2(0, 0);
        if (lane < deg) os_l = bos[lane];
        int   e_l = os_l.x;
        float pe  = (lane < deg) ? expf(__int_as_float(os_l.y)) : 0.f;
        float sum = pe;
        #pragma unroll
        for (int off = 32; off > 0; off >>= 1) sum += __shfl_xor(sum, off);
        float inv  = sum > 0.f ? 1.f / sum : 0.f;
        float pw_l = pe * inv;

        int grp = lane >> 3, sub = lane & 7;
        float4 a0 = make_float4(0.f, 0.f, 0.f, 0.f);
        float4 a1 = a0, a2 = a0, a3 = a0;
        int kmax = (deg + 7) >> 3;
        for (int k = 0; k < kmax; ++k) {
            int j  = grp + 8 * k;
            int jj = (j < deg) ? j : 0;           // shfl src stays a valid lane
            int   e  = __shfl(e_l, jj);           // uniform-active shfl
            float pw = __shfl(pw_l, jj);
            if (j < deg) {
                const float* er = ef + (size_t)e * DD;
                float4 v0 = ntload4(er + sub * 4);
                float4 v1 = ntload4(er + 32 + sub * 4);
                float4 v2 = ntload4(er + 64 + sub * 4);
                float4 v3 = ntload4(er + 96 + sub * 4);
                a0.x = fmaf(pw, v0.x, a0.x); a0.y = fmaf(pw, v0.y, a0.y);
                a0.z = fmaf(pw, v0.z, a0.z); a0.w = fmaf(pw, v0.w, a0.w);
                a1.x = fmaf(pw, v1.x, a1.x); a1.y = fmaf(pw, v1.y, a1.y);
                a1.z = fmaf(pw, v1.z, a1.z); a1.w = fmaf(pw, v1.w, a1.w);
                a2.x = fmaf(pw, v2.x, a2.x); a2.y = fmaf(pw, v2.y, a2.y);
                a2.z = fmaf(pw, v2.z, a2.z); a2.w = fmaf(pw, v2.w, a2.w);
                a3.x = fmaf(pw, v3.x, a3.x); a3.y = fmaf(pw, v3.y, a3.y);
                a3.z = fmaf(pw, v3.z, a3.z); a3.w = fmaf(pw, v3.w, a3.w);
            }
        }
        #pragma unroll
        for (int off = 8; off <= 32; off <<= 1) {
            a0.x += __shfl_xor(a0.x, off); a0.y += __shfl_xor(a0.y, off);
            a0.z += __shfl_xor(a0.z, off); a0.w += __shfl_xor(a0.w, off);
            a1.x += __shfl_xor(a1.x, off); a1.y += __shfl_xor(a1.y, off);
            a1.z += __shfl_xor(a1.z, off); a1.w += __shfl_xor(a1.w, off);
            a2.x += __shfl_xor(a2.x, off); a2.y += __shfl_xor(a2.y, off);
            a2.z += __shfl_xor(a2.z, off); a2.w += __shfl_xor(a2.w, off);
            a3.x += __shfl_xor(a3.x, off); a3.y += __shfl_xor(a3.y, off);
            a3.z += __shfl_xor(a3.z, off); a3.w += __shfl_xor(a3.w, off);
        }
        if (lane < 8) {
            ushort* ur = u16 + (size_t)node * DD;
            *reinterpret_cast<ushort4*>(ur + 4 * sub) =
                make_ushort4(f2bf(a0.x), f2bf(a0.y), f2bf(a0.z), f2bf(a0.w));
            *reinterpret_cast<ushort4*>(ur + 32 + 4 * sub) =
                make_ushort4(f2bf(a1.x), f2bf(a1.y), f2bf(a1.z), f2bf(a1.w));
            *reinterpret_cast<ushort4*>(ur + 64 + 4 * sub) =
                make_ushort4(f2bf(a2.x), f2bf(a2.y), f2bf(a2.z), f2bf(a2.w));
            *reinterpret_cast<ushort4*>(ur + 96 + 4 * sub) =
                make_ushort4(f2bf(a3.x), f2bf(a3.y), f2bf(a3.z), f2bf(a3.w));
        }
    } else {
        // ---- overflow path (deg > 64): bucket holds 64, rest in ovf list ----
        int novf = min(*ovf_cnt, OCAP);
        int2 os_l = bos[lane];                       // all 64 slots valid
        float pe  = expf(__int_as_float(os_l.y));
        float sum = pe;
        for (int i = lane; i < novf; i += 64) {
            int4 v = ovf[i];
            if (v.x == node) sum += expf(__int_as_float(v.z));
        }
        #pragma unroll
        for (int off = 32; off > 0; off >>= 1) sum += __shfl_xor(sum, off);
        float inv = sum > 0.f ? 1.f / sum : 0.f;

        float2 acc = make_float2(0.f, 0.f);
        int   e_l = os_l.x;
        float p_l = pe * inv;
        for (int j = 0; j < 64; ++j) {
            int   e  = __shfl(e_l, j);
            float pw = __shfl(p_l, j);
            float2 vv = *reinterpret_cast<const float2*>(ef + (size_t)e * DD + lane * 2);
            acc.x = fmaf(pw, vv.x, acc.x);
            acc.y = fmaf(pw, vv.y, acc.y);
        }
        for (int j = 0; j < novf; ++j) {             // scalar; novf ~ 0
            int4 v = ovf[j];
            if (v.x == node) {
                float pw = expf(__int_as_float(v.z)) * inv;
                float2 vv = *reinterpret_cast<const float2*>(ef + (size_t)v.y * DD + lane * 2);
                acc.x = fmaf(pw, vv.x, acc.x);
                acc.y = fmaf(pw, vv.y, acc.y);
            }
        }
        ushort2 uu; uu.x = f2bf(acc.x); uu.y = f2bf(acc.y);
        *reinterpret_cast<ushort2*>(u16 + (size_t)node * DD + lane * 2) = uu;
    }
}

// ---------------------------------------------------------------------------
// K4: out = relu([h16|u16] @ W16^T + b) via bf16 MFMA (~8 us measured)
// ---------------------------------------------------------------------------
__global__ __launch_bounds__(256) void k_apply_mfma(
    const ushort* __restrict__ h16, const ushort* __restrict__ u16,
    const ushort* __restrict__ W16, const float* __restrict__ b,
    float* __restrict__ out, int n_nodes)
{
    int wave = threadIdx.x >> 6;
    int lane = threadIdx.x & 63;
    int nodeBase = blockIdx.x * 64 + wave * 16;
    int row  = lane & 15;
    int quad = lane >> 4;
    int node = nodeBase + row;
    if (node >= n_nodes) node = n_nodes - 1;   // clamp loads; stores guarded

    f32x4 acc[8];
    #pragma unroll
    for (int ct = 0; ct < 8; ++ct) acc[ct] = (f32x4){0.f, 0.f, 0.f, 0.f};

    #pragma unroll
    for (int kc = 0; kc < 8; ++kc) {
        const ushort* abase = (kc < 4)
            ? (h16 + (size_t)node * DD + kc * 32 + quad * 8)
            : (u16 + (size_t)node * DD + (kc - 4) * 32 + quad * 8);
        short8 a = *reinterpret_cast<const short8*>(abase);
        #pragma unroll
        for (int ct = 0; ct < 8; ++ct) {
            const ushort* wb = W16 + ((size_t)(ct * 16 + row)) * 256 + kc * 32 + quad * 8;
            short8 bb = *reinterpret_cast<const short8*>(wb);
            acc[ct] = __builtin_amdgcn_mfma_f32_16x16x32_bf16(a, bb, acc[ct], 0, 0, 0);
        }
    }

    #pragma unroll
    for (int ct = 0; ct < 8; ++ct) {
        int col = ct * 16 + row;
        float bk = b[col];
        #pragma unroll
        for (int r = 0; r < 4; ++r) {
            int n = nodeBase + quad * 4 + r;
            if (n < n_nodes)
                out[(size_t)n * DD + col] = fmaxf(acc[ct][r] + bk, 0.f);
        }
    }
}

// ---------------------------------------------------------------------------
extern "C" void kernel_launch(void* const* d_in, const int* in_sizes, int n_in,
                              void* d_out, int out_size, void* d_ws, size_t ws_size,
                              hipStream_t stream)
{
    const float* nfeats = (const float*)d_in[0];
    const float* efeats = (const float*)d_in[1];
    const float* W      = (const float*)d_in[2];
    const float* Wb     = (const float*)d_in[3];
    const float* attn_w = (const float*)d_in[4];
    const float* attn_b = (const float*)d_in[5];
    const int*   src    = (const int*)d_in[6];
    const int*   dst    = (const int*)d_in[7];

    const int n_nodes = in_sizes[0] / DD;
    const int n_edges = in_sizes[6];
    const int NDB = (n_nodes + 3) / 4;

    // workspace layout (os_buf 8B-aligned, ovf 16B-aligned)
    char* wsb = (char*)d_ws;
    float*  s_buf   = (float*)wsb;                       wsb += (size_t)n_nodes * 4;
    float*  t_buf   = (float*)wsb;                       wsb += (size_t)n_nodes * 4;
    int*    count   = (int*)wsb;                         wsb += (size_t)n_nodes * 4;
    int*    pad0    = (int*)wsb;                         wsb += (size_t)n_nodes * 4;
    int2*   os_buf  = (int2*)wsb;                        wsb += (size_t)n_nodes * BCAP * 8;
    ushort* h16     = (ushort*)wsb;                      wsb += (size_t)n_nodes * DD * 2;
    ushort* u16     = (ushort*)wsb;                      wsb += (size_t)n_nodes * DD * 2;
    ushort* W16     = (ushort*)wsb;                      wsb += (size_t)128 * 256 * 2;
    int4*   ovf     = (int4*)wsb;                        wsb += (size_t)OCAP * 16;
    int*    ovf_cnt = (int*)wsb;                         wsb += 16;
    (void)pad0;

    k_node_dots<<<NDB + 128, 256, 0, stream>>>(nfeats, attn_w, attn_b, s_buf, t_buf,
                                               count, h16, n_nodes, NDB, W, W16, ovf_cnt);
    k_bucket<<<(n_edges + 255) / 256, 256, 0, stream>>>(dst, src, s_buf, t_buf,
                                                        count, os_buf,
                                                        ovf_cnt, ovf, n_edges);
    k_fused<<<(n_nodes + 3) / 4, 256, 0, stream>>>(count, os_buf, efeats,
                                                   ovf_cnt, ovf, u16, n_nodes);
    k_apply_mfma<<<(n_nodes + 63) / 64, 256, 0, stream>>>(h16, u16, W16, Wb,
                                                          (float*)d_out, n_nodes);
}

// Round 15
// 172.021 us; speedup vs baseline: 13.5087x; 1.0013x over previous
//
#include <hip/hip_runtime.h>

#define DD 128
#define BCAP 64
#define OCAP 4096

typedef float vfloat4 __attribute__((ext_vector_type(4)));
typedef __attribute__((ext_vector_type(8))) short short8;   // 8 bf16 = 4 VGPRs
typedef __attribute__((ext_vector_type(4))) float f32x4;    // MFMA accumulator

__device__ inline float4 ntload4(const float* p) {
    vfloat4 v = __builtin_nontemporal_load(reinterpret_cast<const vfloat4*>(p));
    return make_float4(v.x, v.y, v.z, v.w);
}

// round-to-nearest-even f32 -> bf16 (as ushort)
__device__ inline ushort f2bf(float f) {
    unsigned x = __float_as_uint(f);
    return (ushort)((x + 0x7FFFu + ((x >> 16) & 1u)) >> 16);
}

// ---------------------------------------------------------------------------
// K1: per-node dots s[n]=h·aw_src, t[n]=h·aw_dst+attn_b; zeroes count[n];
// writes h16. Tail blocks cast W -> W16. gid 0 zeroes the overflow counter.
// ---------------------------------------------------------------------------
__global__ __launch_bounds__(256) void k_node_dots(
    const float* __restrict__ h, const float* __restrict__ attn_w,
    const float* __restrict__ attn_b,
    float* __restrict__ s, float* __restrict__ t,
    int* __restrict__ count, ushort* __restrict__ h16,
    int n_nodes, int n_node_blocks,
    const float* __restrict__ W, ushort* __restrict__ W16,
    int* __restrict__ ovf_cnt)
{
    if (blockIdx.x >= n_node_blocks) {
        int idx = (blockIdx.x - n_node_blocks) * 256 + threadIdx.x;
        if (idx < 128 * 256) W16[idx] = f2bf(W[idx]);
        return;
    }
    int gid  = blockIdx.x * blockDim.x + threadIdx.x;
    if (gid == 0) *ovf_cnt = 0;
    int node = gid >> 6;
    int lane = threadIdx.x & 63;
    if (node >= n_nodes) return;
    const float2 hv = *reinterpret_cast<const float2*>(h + (size_t)node * DD + lane * 2);
    const float2 as = *reinterpret_cast<const float2*>(attn_w + lane * 2);
    const float2 ad = *reinterpret_cast<const float2*>(attn_w + DD + lane * 2);
    ushort2 hb; hb.x = f2bf(hv.x); hb.y = f2bf(hv.y);
    *reinterpret_cast<ushort2*>(h16 + (size_t)node * DD + lane * 2) = hb;
    float sa = hv.x * as.x + hv.y * as.y;
    float ta = hv.x * ad.x + hv.y * ad.y;
    #pragma unroll
    for (int off = 32; off > 0; off >>= 1) {
        sa += __shfl_down(sa, off);
        ta += __shfl_down(ta, off);
    }
    if (lane == 0) { s[node] = sa; t[node] = ta + attn_b[0]; count[node] = 0; }
}

// ---------------------------------------------------------------------------
// K2: bucketize (replaces hist+scan+scatter): rank = returning atomicAdd,
// edge {id,score} lands at os[dst*64+rank]; rank >= 64 spills to overflow.
// ~35 us measured: bound by atomic write-through, structural minimum here.
// ---------------------------------------------------------------------------
__global__ __launch_bounds__(256) void k_bucket(
    const int* __restrict__ dst, const int* __restrict__ src,
    const float* __restrict__ s, const float* __restrict__ t,
    int* __restrict__ count,
    int2* __restrict__ os, int* __restrict__ ovf_cnt, int4* __restrict__ ovf,
    int n_edges)
{
    int e = blockIdx.x * blockDim.x + threadIdx.x;
    if (e >= n_edges) return;
    int d = dst[e];
    float sc = fmaxf(s[src[e]] + t[d], 0.f);
    int r = atomicAdd(count + d, 1);
    if (r < BCAP) {
        int2 v; v.x = e; v.y = __float_as_int(sc);
        os[(size_t)d * BCAP + r] = v;
    } else {
        int oi = atomicAdd(ovf_cnt, 1);
        if (oi < OCAP) {
            int4 v; v.x = d; v.y = e; v.z = __float_as_int(sc); v.w = 0;
            ovf[oi] = v;
        }
    }
}

// ---------------------------------------------------------------------------
// K3: fused per-node attention from buckets (measured ~64 us = HBM roofline
// on the mandatory 410 MB efeats read). deg<=64 fast path is register-only.
// ---------------------------------------------------------------------------
__global__ __launch_bounds__(256) void k_fused(
    const int* __restrict__ count, const int2* __restrict__ os,
    const float* __restrict__ ef,
    const int* __restrict__ ovf_cnt, const int4* __restrict__ ovf,
    ushort* __restrict__ u16, int n_nodes)
{
    int node = blockIdx.x * (blockDim.x >> 6) + (threadIdx.x >> 6);
    int lane = threadIdx.x & 63;
    if (node >= n_nodes) return;
    int deg = count[node];
    const int2* bos = os + (size_t)node * BCAP;

    if (deg <= 64) {
        int2 os_l = make_int2(0, 0);
        if (lane < deg) os_l = bos[lane];
        int   e_l = os_l.x;
        float pe  = (lane < deg) ? expf(__int_as_float(os_l.y)) : 0.f;
        float sum = pe;
        #pragma unroll
        for (int off = 32; off > 0; off >>= 1) sum += __shfl_xor(sum, off);
        float inv  = sum > 0.f ? 1.f / sum : 0.f;
        float pw_l = pe * inv;

        int grp = lane >> 3, sub = lane & 7;
        float4 a0 = make_float4(0.f, 0.f, 0.f, 0.f);
        float4 a1 = a0, a2 = a0, a3 = a0;
        int kmax = (deg + 7) >> 3;
        for (int k = 0; k < kmax; ++k) {
            int j  = grp + 8 * k;
            int jj = (j < deg) ? j : 0;           // shfl src stays a valid lane
            int   e  = __shfl(e_l, jj);           // uniform-active shfl
            float pw = __shfl(pw_l, jj);
            if (j < deg) {
                const float* er = ef + (size_t)e * DD;
                float4 v0 = ntload4(er + sub * 4);
                float4 v1 = ntload4(er + 32 + sub * 4);
                float4 v2 = ntload4(er + 64 + sub * 4);
                float4 v3 = ntload4(er + 96 + sub * 4);
                a0.x = fmaf(pw, v0.x, a0.x); a0.y = fmaf(pw, v0.y, a0.y);
                a0.z = fmaf(pw, v0.z, a0.z); a0.w = fmaf(pw, v0.w, a0.w);
                a1.x = fmaf(pw, v1.x, a1.x); a1.y = fmaf(pw, v1.y, a1.y);
                a1.z = fmaf(pw, v1.z, a1.z); a1.w = fmaf(pw, v1.w, a1.w);
                a2.x = fmaf(pw, v2.x, a2.x); a2.y = fmaf(pw, v2.y, a2.y);
                a2.z = fmaf(pw, v2.z, a2.z); a2.w = fmaf(pw, v2.w, a2.w);
                a3.x = fmaf(pw, v3.x, a3.x); a3.y = fmaf(pw, v3.y, a3.y);
                a3.z = fmaf(pw, v3.z, a3.z); a3.w = fmaf(pw, v3.w, a3.w);
            }
        }
        #pragma unroll
        for (int off = 8; off <= 32; off <<= 1) {
            a0.x += __shfl_xor(a0.x, off); a0.y += __shfl_xor(a0.y, off);
            a0.z += __shfl_xor(a0.z, off); a0.w += __shfl_xor(a0.w, off);
            a1.x += __shfl_xor(a1.x, off); a1.y += __shfl_xor(a1.y, off);
            a1.z += __shfl_xor(a1.z, off); a1.w += __shfl_xor(a1.w, off);
            a2.x += __shfl_xor(a2.x, off); a2.y += __shfl_xor(a2.y, off);
            a2.z += __shfl_xor(a2.z, off); a2.w += __shfl_xor(a2.w, off);
            a3.x += __shfl_xor(a3.x, off); a3.y += __shfl_xor(a3.y, off);
            a3.z += __shfl_xor(a3.z, off); a3.w += __shfl_xor(a3.w, off);
        }
        if (lane < 8) {
            ushort* ur = u16 + (size_t)node * DD;
            *reinterpret_cast<ushort4*>(ur + 4 * sub) =
                make_ushort4(f2bf(a0.x), f2bf(a0.y), f2bf(a0.z), f2bf(a0.w));
            *reinterpret_cast<ushort4*>(ur + 32 + 4 * sub) =
                make_ushort4(f2bf(a1.x), f2bf(a1.y), f2bf(a1.z), f2bf(a1.w));
            *reinterpret_cast<ushort4*>(ur + 64 + 4 * sub) =
                make_ushort4(f2bf(a2.x), f2bf(a2.y), f2bf(a2.z), f2bf(a2.w));
            *reinterpret_cast<ushort4*>(ur + 96 + 4 * sub) =
                make_ushort4(f2bf(a3.x), f2bf(a3.y), f2bf(a3.z), f2bf(a3.w));
        }
    } else {
        // ---- overflow path (deg > 64): bucket holds 64, rest in ovf list ----
        int novf = min(*ovf_cnt, OCAP);
        int2 os_l = bos[lane];                       // all 64 slots valid
        float pe  = expf(__int_as_float(os_l.y));
        float sum = pe;
        for (int i = lane; i < novf; i += 64) {
            int4 v = ovf[i];
            if (v.x == node) sum += expf(__int_as_float(v.z));
        }
        #pragma unroll
        for (int off = 32; off > 0; off >>= 1) sum += __shfl_xor(sum, off);
        float inv = sum > 0.f ? 1.f / sum : 0.f;

        float2 acc = make_float2(0.f, 0.f);
        int   e_l = os_l.x;
        float p_l = pe * inv;
        for (int j = 0; j < 64; ++j) {
            int   e  = __shfl(e_l, j);
            float pw = __shfl(p_l, j);
            float2 vv = *reinterpret_cast<const float2*>(ef + (size_t)e * DD + lane * 2);
            acc.x = fmaf(pw, vv.x, acc.x);
            acc.y = fmaf(pw, vv.y, acc.y);
        }
        for (int j = 0; j < novf; ++j) {             // scalar; novf ~ 0
            int4 v = ovf[j];
            if (v.x == node) {
                float pw = expf(__int_as_float(v.z)) * inv;
                float2 vv = *reinterpret_cast<const float2*>(ef + (size_t)v.y * DD + lane * 2);
                acc.x = fmaf(pw, vv.x, acc.x);
                acc.y = fmaf(pw, vv.y, acc.y);
            }
        }
        ushort2 uu; uu.x = f2bf(acc.x); uu.y = f2bf(acc.y);
        *reinterpret_cast<ushort2*>(u16 + (size_t)node * DD + lane * 2) = uu;
    }
}

// ---------------------------------------------------------------------------
// K4: out = relu([h16|u16] @ W16^T + b) via bf16 MFMA (~8 us measured)
// ---------------------------------------------------------------------------
__global__ __launch_bounds__(256) void k_apply_mfma(
    const ushort* __restrict__ h16, const ushort* __restrict__ u16,
    const ushort* __restrict__ W16, const float* __restrict__ b,
    float* __restrict__ out, int n_nodes)
{
    int wave = threadIdx.x >> 6;
    int lane = threadIdx.x & 63;
    int nodeBase = blockIdx.x * 64 + wave * 16;
    int row  = lane & 15;
    int quad = lane >> 4;
    int node = nodeBase + row;
    if (node >= n_nodes) node = n_nodes - 1;   // clamp loads; stores guarded

    f32x4 acc[8];
    #pragma unroll
    for (int ct = 0; ct < 8; ++ct) acc[ct] = (f32x4){0.f, 0.f, 0.f, 0.f};

    #pragma unroll
    for (int kc = 0; kc < 8; ++kc) {
        const ushort* abase = (kc < 4)
            ? (h16 + (size_t)node * DD + kc * 32 + quad * 8)
            : (u16 + (size_t)node * DD + (kc - 4) * 32 + quad * 8);
        short8 a = *reinterpret_cast<const short8*>(abase);
        #pragma unroll
        for (int ct = 0; ct < 8; ++ct) {
            const ushort* wb = W16 + ((size_t)(ct * 16 + row)) * 256 + kc * 32 + quad * 8;
            short8 bb = *reinterpret_cast<const short8*>(wb);
            acc[ct] = __builtin_amdgcn_mfma_f32_16x16x32_bf16(a, bb, acc[ct], 0, 0, 0);
        }
    }

    #pragma unroll
    for (int ct = 0; ct < 8; ++ct) {
        int col = ct * 16 + row;
        float bk = b[col];
        #pragma unroll
        for (int r = 0; r < 4; ++r) {
            int n = nodeBase + quad * 4 + r;
            if (n < n_nodes)
                out[(size_t)n * DD + col] = fmaxf(acc[ct][r] + bk, 0.f);
        }
    }
}

// ---------------------------------------------------------------------------
extern "C" void kernel_launch(void* const* d_in, const int* in_sizes, int n_in,
                              void* d_out, int out_size, void* d_ws, size_t ws_size,
                              hipStream_t stream)
{
    const float* nfeats = (const float*)d_in[0];
    const float* efeats = (const float*)d_in[1];
    const float* W      = (const float*)d_in[2];
    const float* Wb     = (const float*)d_in[3];
    const float* attn_w = (const float*)d_in[4];
    const float* attn_b = (const float*)d_in[5];
    const int*   src    = (const int*)d_in[6];
    const int*   dst    = (const int*)d_in[7];

    const int n_nodes = in_sizes[0] / DD;
    const int n_edges = in_sizes[6];
    const int NDB = (n_nodes + 3) / 4;

    // workspace layout (os_buf 8B-aligned, ovf 16B-aligned)
    char* wsb = (char*)d_ws;
    float*  s_buf   = (float*)wsb;                       wsb += (size_t)n_nodes * 4;
    float*  t_buf   = (float*)wsb;                       wsb += (size_t)n_nodes * 4;
    int*    count   = (int*)wsb;                         wsb += (size_t)n_nodes * 4;
    int*    pad0    = (int*)wsb;                         wsb += (size_t)n_nodes * 4;
    int2*   os_buf  = (int2*)wsb;                        wsb += (size_t)n_nodes * BCAP * 8;
    ushort* h16     = (ushort*)wsb;                      wsb += (size_t)n_nodes * DD * 2;
    ushort* u16     = (ushort*)wsb;                      wsb += (size_t)n_nodes * DD * 2;
    ushort* W16     = (ushort*)wsb;                      wsb += (size_t)128 * 256 * 2;
    int4*   ovf     = (int4*)wsb;                        wsb += (size_t)OCAP * 16;
    int*    ovf_cnt = (int*)wsb;                         wsb += 16;
    (void)pad0;

    k_node_dots<<<NDB + 128, 256, 0, stream>>>(nfeats, attn_w, attn_b, s_buf, t_buf,
                                               count, h16, n_nodes, NDB, W, W16, ovf_cnt);
    k_bucket<<<(n_edges + 255) / 256, 256, 0, stream>>>(dst, src, s_buf, t_buf,
                                                        count, os_buf,
                                                        ovf_cnt, ovf, n_edges);
    k_fused<<<(n_nodes + 3) / 4, 256, 0, stream>>>(count, os_buf, efeats,
                                                   ovf_cnt, ovf, u16, n_nodes);
    k_apply_mfma<<<(n_nodes + 63) / 64, 256, 0, stream>>>(h16, u16, W16, Wb,
                                                          (float*)d_out, n_nodes);
}